// Round 4
// baseline (432.316 us; speedup 1.0000x reference)
//
#include <hip/hip_runtime.h>
#include <hip/hip_bf16.h>

// MHSA_69621419869026 — p=4 sketch linear attention, MI355X gfx950.
// Round 10 == round 9 resubmit (round 9 bench was an infra failure, kernel
// never executed; source re-audit found no faults).
//  * gemm_mfma_fused: epilogue LDS bounce OVERLAYS As/Bs (18.4 KB total,
//    was 34.8 KB) -> occupancy back up; read-swizzle reverted (r8 showed the
//    b128 pattern is already at the structural 8-cycle minimum).
//  * grid order j-fastest for both GEMMs (xb/OAb panels fetched ~once; r8
//    showed 5x re-fetch with token-fastest order).
//  * prep kernels (convert_x / convert_wT / precompute_wc) merged into one
//    launch; kv split-K 32 -> 16 segments.
// Dims: B=4 S=8192 D=512 H=8 HD=R=64, N=B*S=32768.

#define SEQ 8192

typedef __attribute__((ext_vector_type(8))) short bf16x8;
typedef __attribute__((ext_vector_type(4))) float f32x4;

__device__ __forceinline__ unsigned short f2b(float f) {
    union { float f; unsigned int i; } v; v.f = f;
    unsigned int r = v.i + 0x7fffu + ((v.i >> 16) & 1u);   // RNE
    return (unsigned short)(r >> 16);
}
__device__ __forceinline__ float b2f(unsigned short u) {
    union { unsigned int i; float f; } v; v.i = ((unsigned int)u) << 16; return v.f;
}

#if __has_builtin(__builtin_amdgcn_global_load_lds)
#define ASYNC_CP 1
#endif

__device__ __forceinline__ void cp16(const unsigned short* g, unsigned short* l) {
#ifdef ASYNC_CP
    __builtin_amdgcn_global_load_lds(
        (const __attribute__((address_space(1))) unsigned int*)g,
        (__attribute__((address_space(3))) unsigned int*)l, 16, 0, 0);
#endif
}

// ---------------- merged pre-pass --------------------------------------------
// blocks [0,8192): convert_x;  [8192,8704): convert_wT;  [8704,9217): wc + bv.
__global__ __launch_bounds__(256) void prep_all(
    const float* __restrict__ x, unsigned short* __restrict__ xb,
    const float* __restrict__ Wv, const float* __restrict__ Wp,
    unsigned short* __restrict__ WTf, unsigned short* __restrict__ WTp,
    const float* __restrict__ Wq, const float* __restrict__ bq,
    const float* __restrict__ Wk, const float* __restrict__ bk,
    const float* __restrict__ bv,
    const float* __restrict__ gq, const float* __restrict__ bbq,
    const float* __restrict__ gk, const float* __restrict__ bbk,
    const float* __restrict__ qG1, const float* __restrict__ qG2,
    const float* __restrict__ kG1, const float* __restrict__ kG2,
    float* __restrict__ cvec)
{
    const int blk = blockIdx.x;
    const int tid = threadIdx.x;

    if (blk < 8192) {                       // ---- convert_x ----
        size_t i = ((size_t)blk * 256 + tid) * 8;
        float4 a = *(const float4*)&x[i];
        float4 b = *(const float4*)&x[i + 4];
        ushort4 o1 = { f2b(a.x), f2b(a.y), f2b(a.z), f2b(a.w) };
        ushort4 o2 = { f2b(b.x), f2b(b.y), f2b(b.z), f2b(b.w) };
        *(ushort4*)&xb[i]     = o1;
        *(ushort4*)&xb[i + 4] = o2;
        return;
    }

    if (blk < 8704) {                       // ---- convert_wT ----
        const int idx = blk - 8192;
        const int z = idx >> 8;
        const float* W = (z == 0) ? Wv : Wp;
        unsigned short* O = (z == 0) ? (WTf + (size_t)2048 * 512) : WTp;
        __shared__ float t[32][33];
        const int tx = tid & 31, ty = tid >> 5;
        const int k0 = ((idx >> 4) & 15) * 32, n0 = (idx & 15) * 32;
        #pragma unroll
        for (int i = 0; i < 4; ++i)
            t[ty + 8 * i][tx] = W[(size_t)(k0 + ty + 8 * i) * 512 + n0 + tx];
        __syncthreads();
        #pragma unroll
        for (int i = 0; i < 4; ++i)
            O[(size_t)(n0 + ty + 8 * i) * 512 + k0 + tx] = f2b(t[tx][ty + 8 * i]);
        return;
    }

    // ---- precompute_wc ----
    const int idx = blk - 8704;
    if (idx == 512) {
        for (int i = tid; i < 512; i += 256) cvec[2048 + i] = bv[i];
        return;
    }
    const int bi = idx & 31, ky = idx >> 5;
    const int zz = bi >> 4, h = (bi >> 1) & 7, p = bi & 1;
    const float* W    = zz ? Wk : Wq;
    const float* bias = zz ? bk : bq;
    const float* G    = zz ? (p ? kG2 : kG1) : (p ? qG2 : qG1);
    const float  gamma = zz ? gk[0] : gq[0];
    const float  beta  = zz ? bbk[0] : bbq[0];

    __shared__ float Gs[64][65];
    for (int i = tid; i < 4096; i += 256) Gs[i >> 6][i & 63] = G[i];
    __syncthreads();

    const int rr = tid & 63, kg = tid >> 6;
    const int jc = zz * 1024 + h * 128 + rr * 2 + p;
    const int k0 = ky * 32;
    for (int k = k0 + kg; k < k0 + 32; k += 4) {
        float s = 0.f;
        const float* wrow = &W[(size_t)k * 512 + h * 64];
        #pragma unroll 8
        for (int j = 0; j < 64; ++j) s = fmaf(wrow[j], Gs[j][rr], s);
        WTf[(size_t)jc * 512 + k] = f2b(gamma * s);
    }
    if (kg == 0 && ky == 0) {
        float cb = 0.f, cg = 0.f;
        #pragma unroll 8
        for (int j = 0; j < 64; ++j) {
            cb = fmaf(bias[h * 64 + j], Gs[j][rr], cb);
            cg += Gs[j][rr];
        }
        cvec[jc] = gamma * cb + beta * cg;
    }
}

// ---------------- fused MFMA GEMM: U = x @ WC, phi/v epilogue ----------------
// grid (20 j-tiles, 256 token-tiles) — j FASTEST so resident blocks share the
// same xb token panel (fetch xb ~once). 128x128 tile, 4 waves.
// Epilogue bounce buffer OVERLAYS As/Bs (dead after K-loop): LDS = 18.4 KB.
__global__ __launch_bounds__(256) void gemm_mfma_fused(
    const unsigned short* __restrict__ xb,
    const unsigned short* __restrict__ WTf,
    const float* __restrict__ cvec,
    unsigned short* __restrict__ PHIQ, unsigned short* __restrict__ PHIKT,
    unsigned short* __restrict__ VT)
{
    __shared__ __align__(16) unsigned short smem[9216];   // 18 KB
    unsigned short* As = smem;            // 4096 shorts
    unsigned short* Bs = smem + 4096;     // 4096 shorts
    unsigned short* ep = smem;            // epilogue reuse (<= 9216 shorts)

    const int tid = threadIdx.x;
    const int w = tid >> 6, lane = tid & 63;
    const int j0 = blockIdx.x * 128;
    const int n0 = blockIdx.y * 128;
    const int wr = w >> 1, wc = w & 1;

    const int r0 = w * 32 + (lane >> 2);
    const int kq = (lane & 3) * 8;
    const unsigned short* gA = &xb[(size_t)(n0 + r0) * 512 + kq];
    const unsigned short* gB = &WTf[(size_t)(j0 + r0) * 512 + kq];
    unsigned short* lA = As + (w * 32) * 32;
    unsigned short* lB = Bs + (w * 32) * 32;

    f32x4 acc[4][4];
    #pragma unroll
    for (int i = 0; i < 4; ++i)
        #pragma unroll
        for (int j = 0; j < 4; ++j) { acc[i][j] = (f32x4){0.f, 0.f, 0.f, 0.f}; }

    const int cr = (lane >> 4) * 8;

    for (int k0 = 0; k0 < 512; k0 += 32) {
        __syncthreads();
#ifdef ASYNC_CP
        cp16(gA + k0, lA);
        cp16(gA + 16 * 512 + k0, lA + 16 * 32);
        cp16(gB + k0, lB);
        cp16(gB + 16 * 512 + k0, lB + 16 * 32);
#else
        { uint4 v = *(const uint4*)(gA + k0);            *(uint4*)(lA + (size_t)lane * 8) = v; }
        { uint4 v = *(const uint4*)(gA + 16 * 512 + k0); *(uint4*)(lA + 16 * 32 + (size_t)lane * 8) = v; }
        { uint4 v = *(const uint4*)(gB + k0);            *(uint4*)(lB + (size_t)lane * 8) = v; }
        { uint4 v = *(const uint4*)(gB + 16 * 512 + k0); *(uint4*)(lB + 16 * 32 + (size_t)lane * 8) = v; }
#endif
        __syncthreads();

        bf16x8 af[4], bfr[4];
        #pragma unroll
        for (int i = 0; i < 4; ++i) {
            af[i]  = *(const bf16x8*)&As[(wr * 64 + i * 16 + (lane & 15)) * 32 + cr];
            bfr[i] = *(const bf16x8*)&Bs[(wc * 64 + i * 16 + (lane & 15)) * 32 + cr];
        }
        #pragma unroll
        for (int mi = 0; mi < 4; ++mi)
            #pragma unroll
            for (int ni = 0; ni < 4; ++ni)
                acc[mi][ni] = __builtin_amdgcn_mfma_f32_16x16x32_bf16(
                    af[mi], bfr[ni], acc[mi][ni], 0, 0, 0);
    }

    // ---------------- epilogue (j0 is block-uniform) ----------------
    __syncthreads();                   // all waves done reading As/Bs -> ep safe
    const int bq = n0 >> 13;           // batch; 128-token tile is inside one b
    const int sq = n0 & (SEQ - 1);     // first s of tile

    if (j0 < 1024) {
        // ---- phi_q -> PHIQ[b,h,s,r] via LDS bounce [tok][72] (9216 shorts) --
        const int h = j0 >> 7;
        #pragma unroll
        for (int ni = 0; ni < 4; ++ni) {
            const int loc = wc * 64 + ni * 16 + (lane & 15);
            const float cv = cvec[j0 + loc];
            const int rr = loc >> 1;
            #pragma unroll
            for (int mi = 0; mi < 4; ++mi)
                #pragma unroll
                for (int r = 0; r < 4; ++r) {
                    float u = acc[mi][ni][r] + cv;
                    float up = __shfl_xor(u, 1);
                    float hh = 0.125f * u * up;
                    float phi = hh * hh;
                    if ((lane & 1) == 0)
                        ep[(wr * 64 + mi * 16 + (lane >> 4) * 4 + r) * 72 + rr] = f2b(phi);
                }
        }
        __syncthreads();
        for (int i = tid; i < 1024; i += 256) {
            const int tok = i >> 3, ch = i & 7;
            *(uint4*)&PHIQ[((size_t)(bq * 8 + h) * SEQ + sq + tok) * 64 + ch * 8] =
                *(const uint4*)&ep[tok * 72 + ch * 8];
        }
    } else if (j0 < 2048) {
        // ---- phi_k -> PHIKT[b,h,r,s] (transposed) via LDS [rr][136] ----
        const int h = (j0 >> 7) & 7;
        #pragma unroll
        for (int ni = 0; ni < 4; ++ni) {
            const int loc = wc * 64 + ni * 16 + (lane & 15);
            const float cv = cvec[j0 + loc];
            const int rr = loc >> 1;
            #pragma unroll
            for (int mi = 0; mi < 4; ++mi)
                #pragma unroll
                for (int r = 0; r < 4; ++r) {
                    float u = acc[mi][ni][r] + cv;
                    float up = __shfl_xor(u, 1);
                    float hh = 0.125f * u * up;
                    float phi = hh * hh;
                    if ((lane & 1) == 0)
                        ep[rr * 136 + wr * 64 + mi * 16 + (lane >> 4) * 4 + r] = f2b(phi);
                }
        }
        __syncthreads();
        for (int i = tid; i < 1024; i += 256) {
            const int row = i >> 4, ch = i & 15;
            *(uint4*)&PHIKT[((size_t)((bq * 8 + h) * 64 + row)) * SEQ + sq + ch * 8] =
                *(const uint4*)&ep[row * 136 + ch * 8];
        }
    } else {
        // ---- v -> VT[b, h*64+d, s] (transposed), two 64-col halves ----
        #pragma unroll
        for (int half = 0; half < 2; ++half) {
            if (wc == half) {
                #pragma unroll
                for (int ni = 0; ni < 4; ++ni) {
                    const int loc = ni * 16 + (lane & 15);
                    const float cv = cvec[j0 + half * 64 + loc];
                    #pragma unroll
                    for (int mi = 0; mi < 4; ++mi)
                        #pragma unroll
                        for (int r = 0; r < 4; ++r)
                            ep[loc * 136 + wr * 64 + mi * 16 + (lane >> 4) * 4 + r] =
                                f2b(acc[mi][ni][r] + cv);
                }
            }
            __syncthreads();
            for (int i = tid; i < 1024; i += 256) {
                const int row = i >> 4, ch = i & 15;
                const int n = (j0 - 2048) + half * 64 + row;
                *(uint4*)&VT[((size_t)(bq * 512 + n)) * SEQ + sq + ch * 8] =
                    *(const uint4*)&ep[row * 136 + ch * 8];
            }
            __syncthreads();
        }
    }
}

// ---------------- bf16 MFMA GEMM: final projection ---------------------------
// grid (4 j-tiles, 256 token-tiles) — j fastest (OAb panel fetched once).
__global__ __launch_bounds__(256) void gemm_mfma_final(
    const unsigned short* __restrict__ Ab,
    const unsigned short* __restrict__ WTp,
    const float* __restrict__ bias, float* __restrict__ out)
{
    __shared__ __align__(16) unsigned short As[128 * 32];
    __shared__ __align__(16) unsigned short Bs[128 * 32];

    const int tid = threadIdx.x;
    const int w = tid >> 6, lane = tid & 63;
    const int j0 = blockIdx.x * 128;
    const int n0 = blockIdx.y * 128;
    const int wr = w >> 1, wc = w & 1;

    const int r0 = w * 32 + (lane >> 2);
    const int kq = (lane & 3) * 8;
    const unsigned short* gA = &Ab[(size_t)(n0 + r0) * 512 + kq];
    const unsigned short* gB = &WTp[(size_t)(j0 + r0) * 512 + kq];
    unsigned short* lA = &As[(w * 32) * 32];
    unsigned short* lB = &Bs[(w * 32) * 32];

    f32x4 acc[4][4];
    #pragma unroll
    for (int i = 0; i < 4; ++i)
        #pragma unroll
        for (int j = 0; j < 4; ++j) { acc[i][j] = (f32x4){0.f, 0.f, 0.f, 0.f}; }

    const int cr = (lane >> 4) * 8;

    for (int k0 = 0; k0 < 512; k0 += 32) {
        __syncthreads();
#ifdef ASYNC_CP
        cp16(gA + k0, lA);
        cp16(gA + 16 * 512 + k0, lA + 16 * 32);
        cp16(gB + k0, lB);
        cp16(gB + 16 * 512 + k0, lB + 16 * 32);
#else
        { uint4 v = *(const uint4*)(gA + k0);            *(uint4*)(lA + (size_t)lane * 8) = v; }
        { uint4 v = *(const uint4*)(gA + 16 * 512 + k0); *(uint4*)(lA + 16 * 32 + (size_t)lane * 8) = v; }
        { uint4 v = *(const uint4*)(gB + k0);            *(uint4*)(lB + (size_t)lane * 8) = v; }
        { uint4 v = *(const uint4*)(gB + 16 * 512 + k0); *(uint4*)(lB + 16 * 32 + (size_t)lane * 8) = v; }
#endif
        __syncthreads();

        bf16x8 af[4], bfr[4];
        #pragma unroll
        for (int i = 0; i < 4; ++i) {
            af[i]  = *(const bf16x8*)&As[(wr * 64 + i * 16 + (lane & 15)) * 32 + cr];
            bfr[i] = *(const bf16x8*)&Bs[(wc * 64 + i * 16 + (lane & 15)) * 32 + cr];
        }
        #pragma unroll
        for (int mi = 0; mi < 4; ++mi)
            #pragma unroll
            for (int ni = 0; ni < 4; ++ni)
                acc[mi][ni] = __builtin_amdgcn_mfma_f32_16x16x32_bf16(
                    af[mi], bfr[ni], acc[mi][ni], 0, 0, 0);
    }

    #pragma unroll
    for (int ni = 0; ni < 4; ++ni) {
        const int jcol = j0 + wc * 64 + ni * 16 + (lane & 15);
        const float bvv = bias[jcol];
        #pragma unroll
        for (int mi = 0; mi < 4; ++mi) {
            #pragma unroll
            for (int r = 0; r < 4; ++r) {
                const int t = n0 + wr * 64 + mi * 16 + (lane >> 4) * 4 + r;
                out[(size_t)t * 512 + jcol] = acc[mi][ni][r] + bvv;
            }
        }
    }
}

// ---------------- kv = phi_k^T @ v via MFMA, split-K over 16 segments --------
__global__ __launch_bounds__(256) void kv_mfma(
    const unsigned short* __restrict__ PHIKT, const unsigned short* __restrict__ VT,
    float* __restrict__ KVP, float* __restrict__ KSP)
{
    const int bh = blockIdx.x, seg = blockIdx.y;
    const int tid = threadIdx.x;
    const int w = tid >> 6, lane = tid & 63;
    const size_t pbase =
        ((size_t)bh * 64 + w * 16 + (lane & 15)) * SEQ + seg * 512 + (lane >> 4) * 8;
    const size_t vbase =
        ((size_t)((bh >> 3) * 512 + (bh & 7) * 64 + (lane & 15))) * SEQ
        + seg * 512 + (lane >> 4) * 8;

    f32x4 acc[4], ks;
    #pragma unroll
    for (int nt = 0; nt < 4; ++nt) acc[nt] = (f32x4){0.f, 0.f, 0.f, 0.f};
    ks = (f32x4){0.f, 0.f, 0.f, 0.f};
    bf16x8 ones;
    #pragma unroll
    for (int i = 0; i < 8; ++i) ones[i] = (short)0x3f80;   // bf16 1.0

    #pragma unroll 2
    for (int k = 0; k < 512; k += 32) {
        bf16x8 a = *(const bf16x8*)&PHIKT[pbase + k];
        ks = __builtin_amdgcn_mfma_f32_16x16x32_bf16(a, ones, ks, 0, 0, 0);
        #pragma unroll
        for (int nt = 0; nt < 4; ++nt) {
            bf16x8 bb = *(const bf16x8*)&VT[vbase + (size_t)nt * 16 * SEQ + k];
            acc[nt] = __builtin_amdgcn_mfma_f32_16x16x32_bf16(a, bb, acc[nt], 0, 0, 0);
        }
    }

    float* kvp = &KVP[((size_t)bh * 16 + seg) * 4096];
    #pragma unroll
    for (int nt = 0; nt < 4; ++nt) {
        float4 o = { acc[nt][0], acc[nt][1], acc[nt][2], acc[nt][3] };
        *(float4*)&kvp[(nt * 16 + (lane & 15)) * 64 + w * 16 + (lane >> 4) * 4] = o;
    }
    if ((lane & 15) == 0) {
        float4 o = { ks[0], ks[1], ks[2], ks[3] };
        *(float4*)&KSP[((size_t)bh * 16 + seg) * 64 + w * 16 + (lane >> 4) * 4] = o;
    }
}

__global__ __launch_bounds__(256) void kv_reduce(
    const float* __restrict__ KVP, const float* __restrict__ KSP,
    float* __restrict__ KV, float* __restrict__ KS)
{
    const int bh = blockIdx.x;
    const int e0 = blockIdx.y * 512;
    for (int e = e0 + threadIdx.x; e < e0 + 512; e += 256) {
        float s = 0.f;
        #pragma unroll 8
        for (int c = 0; c < 16; ++c) s += KVP[(size_t)(bh * 16 + c) * 4096 + e];
        KV[(size_t)bh * 4096 + e] = s;
    }
    if (blockIdx.y == 0 && threadIdx.x < 64) {
        float s = 0.f;
        for (int c = 0; c < 16; ++c) s += KSP[(bh * 16 + c) * 64 + threadIdx.x];
        KS[bh * 64 + threadIdx.x] = s;
    }
}

// ---------------- out_attn = (phi_q@KV)/(phi_q@ksum+eps) via MFMA ------------
__global__ __launch_bounds__(256) void attn_mfma(
    const unsigned short* __restrict__ PHIQ, const float* __restrict__ KV,
    const float* __restrict__ KS, unsigned short* __restrict__ OAb)
{
    __shared__ __align__(16) unsigned short bpad[144 * 72];
    const int bh = blockIdx.x, st = blockIdx.y;
    const int tid = threadIdx.x;
    const int b = bh >> 3, h = bh & 7;

    for (int i = tid; i < 144 * 64; i += 256) {
        const int n = i >> 6, r = i & 63;
        float val;
        if (n < 64)        val = KV[(size_t)bh * 4096 + n * 64 + r];
        else if (n < 128)  { float x = KV[(size_t)bh * 4096 + (n - 64) * 64 + r];
                             val = x - b2f(f2b(x)); }
        else if (n == 128) val = KS[bh * 64 + r];
        else if (n == 129) { float x = KS[bh * 64 + r]; val = x - b2f(f2b(x)); }
        else               val = 0.f;
        bpad[n * 72 + r] = f2b(val);
    }
    __syncthreads();

    const int w = tid >> 6, lane = tid & 63;
    bf16x8 bf[9][2];
    #pragma unroll
    for (int nt = 0; nt < 9; ++nt) {
        const unsigned short* bp = &bpad[(nt * 16 + (lane & 15)) * 72 + (lane >> 4) * 8];
        bf[nt][0] = *(const bf16x8*)bp;
        bf[nt][1] = *(const bf16x8*)(bp + 32);
    }

    const int tw = st * 256 + w * 64;
    #pragma unroll
    for (int mt = 0; mt < 4; ++mt) {
        const unsigned short* ap =
            &PHIQ[((size_t)bh * SEQ + tw + mt * 16 + (lane & 15)) * 64 + (lane >> 4) * 8];
        bf16x8 a0 = *(const bf16x8*)ap;
        bf16x8 a1 = *(const bf16x8*)(ap + 32);
        f32x4 acc[9];
        #pragma unroll
        for (int nt = 0; nt < 9; ++nt) acc[nt] = (f32x4){0.f, 0.f, 0.f, 0.f};
        #pragma unroll
        for (int nt = 0; nt < 9; ++nt) {
            acc[nt] = __builtin_amdgcn_mfma_f32_16x16x32_bf16(a0, bf[nt][0], acc[nt], 0, 0, 0);
            acc[nt] = __builtin_amdgcn_mfma_f32_16x16x32_bf16(a1, bf[nt][1], acc[nt], 0, 0, 0);
        }
        #pragma unroll
        for (int r4 = 0; r4 < 4; ++r4) {
            const float den = __shfl(acc[8][r4], (lane & 48)) +
                              __shfl(acc[8][r4], (lane & 48) + 1) + 1e-6f;
            const float inv = 1.0f / den;
            const int s = tw + mt * 16 + (lane >> 4) * 4 + r4;
            #pragma unroll
            for (int nt = 0; nt < 4; ++nt)
                OAb[((size_t)b * SEQ + s) * 512 + h * 64 + nt * 16 + (lane & 15)] =
                    f2b((acc[nt][r4] + acc[nt + 4][r4]) * inv);
        }
    }
}

extern "C" void kernel_launch(void* const* d_in, const int* in_sizes, int n_in,
                              void* d_out, int out_size, void* d_ws, size_t ws_size,
                              hipStream_t stream)
{
    (void)in_sizes; (void)n_in; (void)out_size; (void)ws_size;
    const float* x   = (const float*)d_in[0];
    const float* Wq  = (const float*)d_in[1];
    const float* bq  = (const float*)d_in[2];
    const float* Wk  = (const float*)d_in[3];
    const float* bk  = (const float*)d_in[4];
    const float* Wv  = (const float*)d_in[5];
    const float* bv  = (const float*)d_in[6];
    const float* Wp  = (const float*)d_in[7];
    const float* bp  = (const float*)d_in[8];
    const float* gq  = (const float*)d_in[9];
    const float* bbq = (const float*)d_in[10];
    const float* gk  = (const float*)d_in[11];
    const float* bbk = (const float*)d_in[12];
    const float* qG1 = (const float*)d_in[13];
    const float* qG2 = (const float*)d_in[14];
    const float* kG1 = (const float*)d_in[15];
    const float* kG2 = (const float*)d_in[16];

    unsigned short* PHIQ  = (unsigned short*)d_ws;      // 32 MB [b,h,s,r]
    unsigned short* PHIKT = PHIQ + 16777216;            // 32 MB [b,h,r,s]
    unsigned short* VT    = PHIKT + 16777216;           // 32 MB [b,h*64+d,s]
    unsigned short* xb    = VT   + 16777216;            // 32 MB
    unsigned short* OAb   = xb   + 16777216;            // 32 MB
    unsigned short* WTf   = OAb  + 16777216;            // 2.5 MB
    unsigned short* WTp   = WTf  + 2560 * 512;          // 0.5 MB
    float* cvec = (float*)(WTp + 262144);               // 2,560 f
    float* KVP  = cvec + 2560;                          // 8 MB [bh,seg16][d][r]
    float* KSP  = KVP + 4194304;                        // 256 KB (16 segs used)
    float* KV   = KSP + 65536;                          // 512 KB [bh][d][r]
    float* KS   = KV + 131072;                          // 8 KB
    float* out  = (float*)d_out;

    hipLaunchKernelGGL(prep_all, dim3(9217), dim3(256), 0, stream,
                       x, xb, Wv, Wp, WTf, WTp,
                       Wq, bq, Wk, bk, bv, gq, bbq, gk, bbk,
                       qG1, qG2, kG1, kG2, cvec);
    hipLaunchKernelGGL(gemm_mfma_fused, dim3(20, 256), dim3(256), 0, stream,
                       xb, WTf, cvec, PHIQ, PHIKT, VT);
    hipLaunchKernelGGL(kv_mfma, dim3(32, 16), dim3(256), 0, stream,
                       PHIKT, VT, KVP, KSP);
    hipLaunchKernelGGL(kv_reduce, dim3(32, 8), dim3(256), 0, stream, KVP, KSP, KV, KS);
    hipLaunchKernelGGL(attn_mfma, dim3(32, 32), dim3(256), 0, stream,
                       PHIQ, KV, KS, OAb);
    hipLaunchKernelGGL(gemm_mfma_final, dim3(4, 256), dim3(256), 0, stream,
                       OAb, WTp, bp, out);
}

// Round 5
// 409.042 us; speedup vs baseline: 1.0569x; 1.0569x over previous
//
#include <hip/hip_runtime.h>
#include <hip/hip_bf16.h>

// MHSA_69621419869026 — p=4 sketch linear attention, MI355X gfx950.
// Round 11:
//  * gemm_mfma_fused epilogue: back to direct stores (r6 register shape,
//    ~80 VGPR). Transposed PHIKT/VT get FREE ushort4 stores along s (acc reg
//    index = consecutive tokens); PHIQ keeps scattered 2B stores.
//    LDS-bounce removed (it cost 44 VGPR -> occupancy, r10 post-mortem).
//  * XCD-aware swizzle: each XCD owns 32 exclusive token panels x all
//    j-tiles -> xb fetched by exactly one XCD L2 (r10 showed 4x re-fetch
//    from round-robin dispatch). Same for gemm_mfma_final.
//  * downstream (prep_all / kv_mfma / kv_reduce / attn_mfma) unchanged.
// Dims: B=4 S=8192 D=512 H=8 HD=R=64, N=B*S=32768.

#define SEQ 8192

typedef __attribute__((ext_vector_type(8))) short bf16x8;
typedef __attribute__((ext_vector_type(4))) float f32x4;

__device__ __forceinline__ unsigned short f2b(float f) {
    union { float f; unsigned int i; } v; v.f = f;
    unsigned int r = v.i + 0x7fffu + ((v.i >> 16) & 1u);   // RNE
    return (unsigned short)(r >> 16);
}
__device__ __forceinline__ float b2f(unsigned short u) {
    union { unsigned int i; float f; } v; v.i = ((unsigned int)u) << 16; return v.f;
}

#if __has_builtin(__builtin_amdgcn_global_load_lds)
#define ASYNC_CP 1
#endif

__device__ __forceinline__ void cp16(const unsigned short* g, unsigned short* l) {
#ifdef ASYNC_CP
    __builtin_amdgcn_global_load_lds(
        (const __attribute__((address_space(1))) unsigned int*)g,
        (__attribute__((address_space(3))) unsigned int*)l, 16, 0, 0);
#endif
}

// ---------------- merged pre-pass --------------------------------------------
// blocks [0,8192): convert_x;  [8192,8704): convert_wT;  [8704,9217): wc + bv.
__global__ __launch_bounds__(256) void prep_all(
    const float* __restrict__ x, unsigned short* __restrict__ xb,
    const float* __restrict__ Wv, const float* __restrict__ Wp,
    unsigned short* __restrict__ WTf, unsigned short* __restrict__ WTp,
    const float* __restrict__ Wq, const float* __restrict__ bq,
    const float* __restrict__ Wk, const float* __restrict__ bk,
    const float* __restrict__ bv,
    const float* __restrict__ gq, const float* __restrict__ bbq,
    const float* __restrict__ gk, const float* __restrict__ bbk,
    const float* __restrict__ qG1, const float* __restrict__ qG2,
    const float* __restrict__ kG1, const float* __restrict__ kG2,
    float* __restrict__ cvec)
{
    const int blk = blockIdx.x;
    const int tid = threadIdx.x;

    if (blk < 8192) {                       // ---- convert_x ----
        size_t i = ((size_t)blk * 256 + tid) * 8;
        float4 a = *(const float4*)&x[i];
        float4 b = *(const float4*)&x[i + 4];
        ushort4 o1 = { f2b(a.x), f2b(a.y), f2b(a.z), f2b(a.w) };
        ushort4 o2 = { f2b(b.x), f2b(b.y), f2b(b.z), f2b(b.w) };
        *(ushort4*)&xb[i]     = o1;
        *(ushort4*)&xb[i + 4] = o2;
        return;
    }

    if (blk < 8704) {                       // ---- convert_wT ----
        const int idx = blk - 8192;
        const int z = idx >> 8;
        const float* W = (z == 0) ? Wv : Wp;
        unsigned short* O = (z == 0) ? (WTf + (size_t)2048 * 512) : WTp;
        __shared__ float t[32][33];
        const int tx = tid & 31, ty = tid >> 5;
        const int k0 = ((idx >> 4) & 15) * 32, n0 = (idx & 15) * 32;
        #pragma unroll
        for (int i = 0; i < 4; ++i)
            t[ty + 8 * i][tx] = W[(size_t)(k0 + ty + 8 * i) * 512 + n0 + tx];
        __syncthreads();
        #pragma unroll
        for (int i = 0; i < 4; ++i)
            O[(size_t)(n0 + ty + 8 * i) * 512 + k0 + tx] = f2b(t[tx][ty + 8 * i]);
        return;
    }

    // ---- precompute_wc ----
    const int idx = blk - 8704;
    if (idx == 512) {
        for (int i = tid; i < 512; i += 256) cvec[2048 + i] = bv[i];
        return;
    }
    const int bi = idx & 31, ky = idx >> 5;
    const int zz = bi >> 4, h = (bi >> 1) & 7, p = bi & 1;
    const float* W    = zz ? Wk : Wq;
    const float* bias = zz ? bk : bq;
    const float* G    = zz ? (p ? kG2 : kG1) : (p ? qG2 : qG1);
    const float  gamma = zz ? gk[0] : gq[0];
    const float  beta  = zz ? bbk[0] : bbq[0];

    __shared__ float Gs[64][65];
    for (int i = tid; i < 4096; i += 256) Gs[i >> 6][i & 63] = G[i];
    __syncthreads();

    const int rr = tid & 63, kg = tid >> 6;
    const int jc = zz * 1024 + h * 128 + rr * 2 + p;
    const int k0 = ky * 32;
    for (int k = k0 + kg; k < k0 + 32; k += 4) {
        float s = 0.f;
        const float* wrow = &W[(size_t)k * 512 + h * 64];
        #pragma unroll 8
        for (int j = 0; j < 64; ++j) s = fmaf(wrow[j], Gs[j][rr], s);
        WTf[(size_t)jc * 512 + k] = f2b(gamma * s);
    }
    if (kg == 0 && ky == 0) {
        float cb = 0.f, cg = 0.f;
        #pragma unroll 8
        for (int j = 0; j < 64; ++j) {
            cb = fmaf(bias[h * 64 + j], Gs[j][rr], cb);
            cg += Gs[j][rr];
        }
        cvec[jc] = gamma * cb + beta * cg;
    }
}

// ---------------- fused MFMA GEMM: U = x @ WC, phi/v epilogue ----------------
// grid 5120 (flat). XCD swizzle: xcd = flat&7 owns token panels
// [32*xcd, 32*xcd+32) x all 20 j-tiles -> xb panel lives in ONE XCD L2.
// 128x128 tile, 4 waves. Direct stores: PHIKT/VT via ushort4 along s,
// PHIQ via scattered 2B (native [s][r] layout).
__global__ __launch_bounds__(256) void gemm_mfma_fused(
    const unsigned short* __restrict__ xb,
    const unsigned short* __restrict__ WTf,
    const float* __restrict__ cvec,
    unsigned short* __restrict__ PHIQ, unsigned short* __restrict__ PHIKT,
    unsigned short* __restrict__ VT)
{
    __shared__ __align__(16) unsigned short As[128 * 32];
    __shared__ __align__(16) unsigned short Bs[128 * 32];

    const int tid = threadIdx.x;
    const int w = tid >> 6, lane = tid & 63;
    const int flat = blockIdx.x;
    const int xcd = flat & 7, slot = flat >> 3;      // 640 slots per XCD
    const int n0 = (xcd * 32 + slot / 20) * 128;     // token panel (exclusive)
    const int j0 = (slot % 20) * 128;                // j tile
    const int wr = w >> 1, wc = w & 1;

    const int r0 = w * 32 + (lane >> 2);
    const int kq = (lane & 3) * 8;
    const unsigned short* gA = &xb[(size_t)(n0 + r0) * 512 + kq];
    const unsigned short* gB = &WTf[(size_t)(j0 + r0) * 512 + kq];
    unsigned short* lA = &As[(w * 32) * 32];
    unsigned short* lB = &Bs[(w * 32) * 32];

    f32x4 acc[4][4];
    #pragma unroll
    for (int i = 0; i < 4; ++i)
        #pragma unroll
        for (int j = 0; j < 4; ++j) { acc[i][j] = (f32x4){0.f, 0.f, 0.f, 0.f}; }

    const int cr = (lane >> 4) * 8;

    for (int k0 = 0; k0 < 512; k0 += 32) {
        __syncthreads();
#ifdef ASYNC_CP
        cp16(gA + k0, lA);
        cp16(gA + 16 * 512 + k0, lA + 16 * 32);
        cp16(gB + k0, lB);
        cp16(gB + 16 * 512 + k0, lB + 16 * 32);
#else
        { uint4 v = *(const uint4*)(gA + k0);            *(uint4*)(lA + (size_t)lane * 8) = v; }
        { uint4 v = *(const uint4*)(gA + 16 * 512 + k0); *(uint4*)(lA + 16 * 32 + (size_t)lane * 8) = v; }
        { uint4 v = *(const uint4*)(gB + k0);            *(uint4*)(lB + (size_t)lane * 8) = v; }
        { uint4 v = *(const uint4*)(gB + 16 * 512 + k0); *(uint4*)(lB + 16 * 32 + (size_t)lane * 8) = v; }
#endif
        __syncthreads();

        bf16x8 af[4], bfr[4];
        #pragma unroll
        for (int i = 0; i < 4; ++i) {
            af[i]  = *(const bf16x8*)&As[(wr * 64 + i * 16 + (lane & 15)) * 32 + cr];
            bfr[i] = *(const bf16x8*)&Bs[(wc * 64 + i * 16 + (lane & 15)) * 32 + cr];
        }
        #pragma unroll
        for (int mi = 0; mi < 4; ++mi)
            #pragma unroll
            for (int ni = 0; ni < 4; ++ni)
                acc[mi][ni] = __builtin_amdgcn_mfma_f32_16x16x32_bf16(
                    af[mi], bfr[ni], acc[mi][ni], 0, 0, 0);
    }

    // ---------------- epilogue (j0 block-uniform), direct stores ------------
    const int bq = n0 >> 13;                  // batch
    const int sq = n0 & (SEQ - 1);            // first s of tile
    const int t0 = sq + wr * 64 + (lane >> 4) * 4;   // + mi*16 per mi

    if (j0 < 2048) {                          // phi paths (q or k)
        const int zq = j0 >> 10;              // 0 = q, 1 = k (block-uniform)
        const int h  = (j0 >> 7) & 7;
        #pragma unroll
        for (int ni = 0; ni < 4; ++ni) {
            const int loc = wc * 64 + ni * 16 + (lane & 15);
            const float cv = cvec[j0 + loc];
            const int rr = loc >> 1;
            #pragma unroll
            for (int mi = 0; mi < 4; ++mi) {
                float ph[4];
                #pragma unroll
                for (int r = 0; r < 4; ++r) {
                    float u = acc[mi][ni][r] + cv;
                    float up = __shfl_xor(u, 1);
                    float hh = 0.125f * u * up;
                    ph[r] = hh * hh;
                }
                if ((lane & 1) == 0) {
                    if (zq == 0) {
                        // PHIQ[b,h,s,r]: scattered 2B (r6 pattern)
                        #pragma unroll
                        for (int r = 0; r < 4; ++r)
                            PHIQ[((size_t)(bq * 8 + h) * SEQ + t0 + mi * 16 + r) * 64 + rr]
                                = f2b(ph[r]);
                    } else {
                        // PHIKT[b,h,r,s]: 4 consecutive s -> ushort4
                        ushort4 o = { f2b(ph[0]), f2b(ph[1]), f2b(ph[2]), f2b(ph[3]) };
                        *(ushort4*)&PHIKT[((size_t)((bq * 8 + h) * 64 + rr)) * SEQ
                                          + t0 + mi * 16] = o;
                    }
                }
            }
        }
    } else {                                  // v path -> VT[b, n, s]
        #pragma unroll
        for (int ni = 0; ni < 4; ++ni) {
            const int loc = wc * 64 + ni * 16 + (lane & 15);
            const int n = (j0 - 2048) + loc;
            const float cv = cvec[j0 + loc];
            #pragma unroll
            for (int mi = 0; mi < 4; ++mi) {
                ushort4 o = { f2b(acc[mi][ni][0] + cv), f2b(acc[mi][ni][1] + cv),
                              f2b(acc[mi][ni][2] + cv), f2b(acc[mi][ni][3] + cv) };
                *(ushort4*)&VT[((size_t)(bq * 512 + n)) * SEQ + t0 + mi * 16] = o;
            }
        }
    }
}

// ---------------- bf16 MFMA GEMM: final projection ---------------------------
// grid 1024 flat; XCD swizzle: xcd owns 32 token panels x 4 j-tiles.
__global__ __launch_bounds__(256) void gemm_mfma_final(
    const unsigned short* __restrict__ Ab,
    const unsigned short* __restrict__ WTp,
    const float* __restrict__ bias, float* __restrict__ out)
{
    __shared__ __align__(16) unsigned short As[128 * 32];
    __shared__ __align__(16) unsigned short Bs[128 * 32];

    const int tid = threadIdx.x;
    const int w = tid >> 6, lane = tid & 63;
    const int flat = blockIdx.x;
    const int xcd = flat & 7, slot = flat >> 3;      // 128 slots per XCD
    const int n0 = (xcd * 32 + (slot >> 2)) * 128;
    const int j0 = (slot & 3) * 128;
    const int wr = w >> 1, wc = w & 1;

    const int r0 = w * 32 + (lane >> 2);
    const int kq = (lane & 3) * 8;
    const unsigned short* gA = &Ab[(size_t)(n0 + r0) * 512 + kq];
    const unsigned short* gB = &WTp[(size_t)(j0 + r0) * 512 + kq];
    unsigned short* lA = &As[(w * 32) * 32];
    unsigned short* lB = &Bs[(w * 32) * 32];

    f32x4 acc[4][4];
    #pragma unroll
    for (int i = 0; i < 4; ++i)
        #pragma unroll
        for (int j = 0; j < 4; ++j) { acc[i][j] = (f32x4){0.f, 0.f, 0.f, 0.f}; }

    const int cr = (lane >> 4) * 8;

    for (int k0 = 0; k0 < 512; k0 += 32) {
        __syncthreads();
#ifdef ASYNC_CP
        cp16(gA + k0, lA);
        cp16(gA + 16 * 512 + k0, lA + 16 * 32);
        cp16(gB + k0, lB);
        cp16(gB + 16 * 512 + k0, lB + 16 * 32);
#else
        { uint4 v = *(const uint4*)(gA + k0);            *(uint4*)(lA + (size_t)lane * 8) = v; }
        { uint4 v = *(const uint4*)(gA + 16 * 512 + k0); *(uint4*)(lA + 16 * 32 + (size_t)lane * 8) = v; }
        { uint4 v = *(const uint4*)(gB + k0);            *(uint4*)(lB + (size_t)lane * 8) = v; }
        { uint4 v = *(const uint4*)(gB + 16 * 512 + k0); *(uint4*)(lB + 16 * 32 + (size_t)lane * 8) = v; }
#endif
        __syncthreads();

        bf16x8 af[4], bfr[4];
        #pragma unroll
        for (int i = 0; i < 4; ++i) {
            af[i]  = *(const bf16x8*)&As[(wr * 64 + i * 16 + (lane & 15)) * 32 + cr];
            bfr[i] = *(const bf16x8*)&Bs[(wc * 64 + i * 16 + (lane & 15)) * 32 + cr];
        }
        #pragma unroll
        for (int mi = 0; mi < 4; ++mi)
            #pragma unroll
            for (int ni = 0; ni < 4; ++ni)
                acc[mi][ni] = __builtin_amdgcn_mfma_f32_16x16x32_bf16(
                    af[mi], bfr[ni], acc[mi][ni], 0, 0, 0);
    }

    #pragma unroll
    for (int ni = 0; ni < 4; ++ni) {
        const int jcol = j0 + wc * 64 + ni * 16 + (lane & 15);
        const float bvv = bias[jcol];
        #pragma unroll
        for (int mi = 0; mi < 4; ++mi) {
            #pragma unroll
            for (int r = 0; r < 4; ++r) {
                const int t = n0 + wr * 64 + mi * 16 + (lane >> 4) * 4 + r;
                out[(size_t)t * 512 + jcol] = acc[mi][ni][r] + bvv;
            }
        }
    }
}

// ---------------- kv = phi_k^T @ v via MFMA, split-K over 16 segments --------
__global__ __launch_bounds__(256) void kv_mfma(
    const unsigned short* __restrict__ PHIKT, const unsigned short* __restrict__ VT,
    float* __restrict__ KVP, float* __restrict__ KSP)
{
    const int bh = blockIdx.x, seg = blockIdx.y;
    const int tid = threadIdx.x;
    const int w = tid >> 6, lane = tid & 63;
    const size_t pbase =
        ((size_t)bh * 64 + w * 16 + (lane & 15)) * SEQ + seg * 512 + (lane >> 4) * 8;
    const size_t vbase =
        ((size_t)((bh >> 3) * 512 + (bh & 7) * 64 + (lane & 15))) * SEQ
        + seg * 512 + (lane >> 4) * 8;

    f32x4 acc[4], ks;
    #pragma unroll
    for (int nt = 0; nt < 4; ++nt) acc[nt] = (f32x4){0.f, 0.f, 0.f, 0.f};
    ks = (f32x4){0.f, 0.f, 0.f, 0.f};
    bf16x8 ones;
    #pragma unroll
    for (int i = 0; i < 8; ++i) ones[i] = (short)0x3f80;   // bf16 1.0

    #pragma unroll 2
    for (int k = 0; k < 512; k += 32) {
        bf16x8 a = *(const bf16x8*)&PHIKT[pbase + k];
        ks = __builtin_amdgcn_mfma_f32_16x16x32_bf16(a, ones, ks, 0, 0, 0);
        #pragma unroll
        for (int nt = 0; nt < 4; ++nt) {
            bf16x8 bb = *(const bf16x8*)&VT[vbase + (size_t)nt * 16 * SEQ + k];
            acc[nt] = __builtin_amdgcn_mfma_f32_16x16x32_bf16(a, bb, acc[nt], 0, 0, 0);
        }
    }

    float* kvp = &KVP[((size_t)bh * 16 + seg) * 4096];
    #pragma unroll
    for (int nt = 0; nt < 4; ++nt) {
        float4 o = { acc[nt][0], acc[nt][1], acc[nt][2], acc[nt][3] };
        *(float4*)&kvp[(nt * 16 + (lane & 15)) * 64 + w * 16 + (lane >> 4) * 4] = o;
    }
    if ((lane & 15) == 0) {
        float4 o = { ks[0], ks[1], ks[2], ks[3] };
        *(float4*)&KSP[((size_t)bh * 16 + seg) * 64 + w * 16 + (lane >> 4) * 4] = o;
    }
}

__global__ __launch_bounds__(256) void kv_reduce(
    const float* __restrict__ KVP, const float* __restrict__ KSP,
    float* __restrict__ KV, float* __restrict__ KS)
{
    const int bh = blockIdx.x;
    const int e0 = blockIdx.y * 512;
    for (int e = e0 + threadIdx.x; e < e0 + 512; e += 256) {
        float s = 0.f;
        #pragma unroll 8
        for (int c = 0; c < 16; ++c) s += KVP[(size_t)(bh * 16 + c) * 4096 + e];
        KV[(size_t)bh * 4096 + e] = s;
    }
    if (blockIdx.y == 0 && threadIdx.x < 64) {
        float s = 0.f;
        for (int c = 0; c < 16; ++c) s += KSP[(bh * 16 + c) * 64 + threadIdx.x];
        KS[bh * 64 + threadIdx.x] = s;
    }
}

// ---------------- out_attn = (phi_q@KV)/(phi_q@ksum+eps) via MFMA ------------
__global__ __launch_bounds__(256) void attn_mfma(
    const unsigned short* __restrict__ PHIQ, const float* __restrict__ KV,
    const float* __restrict__ KS, unsigned short* __restrict__ OAb)
{
    __shared__ __align__(16) unsigned short bpad[144 * 72];
    const int bh = blockIdx.x, st = blockIdx.y;
    const int tid = threadIdx.x;
    const int b = bh >> 3, h = bh & 7;

    for (int i = tid; i < 144 * 64; i += 256) {
        const int n = i >> 6, r = i & 63;
        float val;
        if (n < 64)        val = KV[(size_t)bh * 4096 + n * 64 + r];
        else if (n < 128)  { float x = KV[(size_t)bh * 4096 + (n - 64) * 64 + r];
                             val = x - b2f(f2b(x)); }
        else if (n == 128) val = KS[bh * 64 + r];
        else if (n == 129) { float x = KS[bh * 64 + r]; val = x - b2f(f2b(x)); }
        else               val = 0.f;
        bpad[n * 72 + r] = f2b(val);
    }
    __syncthreads();

    const int w = tid >> 6, lane = tid & 63;
    bf16x8 bf[9][2];
    #pragma unroll
    for (int nt = 0; nt < 9; ++nt) {
        const unsigned short* bp = &bpad[(nt * 16 + (lane & 15)) * 72 + (lane >> 4) * 8];
        bf[nt][0] = *(const bf16x8*)bp;
        bf[nt][1] = *(const bf16x8*)(bp + 32);
    }

    const int tw = st * 256 + w * 64;
    #pragma unroll
    for (int mt = 0; mt < 4; ++mt) {
        const unsigned short* ap =
            &PHIQ[((size_t)bh * SEQ + tw + mt * 16 + (lane & 15)) * 64 + (lane >> 4) * 8];
        bf16x8 a0 = *(const bf16x8*)ap;
        bf16x8 a1 = *(const bf16x8*)(ap + 32);
        f32x4 acc[9];
        #pragma unroll
        for (int nt = 0; nt < 9; ++nt) acc[nt] = (f32x4){0.f, 0.f, 0.f, 0.f};
        #pragma unroll
        for (int nt = 0; nt < 9; ++nt) {
            acc[nt] = __builtin_amdgcn_mfma_f32_16x16x32_bf16(a0, bf[nt][0], acc[nt], 0, 0, 0);
            acc[nt] = __builtin_amdgcn_mfma_f32_16x16x32_bf16(a1, bf[nt][1], acc[nt], 0, 0, 0);
        }
        #pragma unroll
        for (int r4 = 0; r4 < 4; ++r4) {
            const float den = __shfl(acc[8][r4], (lane & 48)) +
                              __shfl(acc[8][r4], (lane & 48) + 1) + 1e-6f;
            const float inv = 1.0f / den;
            const int s = tw + mt * 16 + (lane >> 4) * 4 + r4;
            #pragma unroll
            for (int nt = 0; nt < 4; ++nt)
                OAb[((size_t)b * SEQ + s) * 512 + h * 64 + nt * 16 + (lane & 15)] =
                    f2b((acc[nt][r4] + acc[nt + 4][r4]) * inv);
        }
    }
}

extern "C" void kernel_launch(void* const* d_in, const int* in_sizes, int n_in,
                              void* d_out, int out_size, void* d_ws, size_t ws_size,
                              hipStream_t stream)
{
    (void)in_sizes; (void)n_in; (void)out_size; (void)ws_size;
    const float* x   = (const float*)d_in[0];
    const float* Wq  = (const float*)d_in[1];
    const float* bq  = (const float*)d_in[2];
    const float* Wk  = (const float*)d_in[3];
    const float* bk  = (const float*)d_in[4];
    const float* Wv  = (const float*)d_in[5];
    const float* bv  = (const float*)d_in[6];
    const float* Wp  = (const float*)d_in[7];
    const float* bp  = (const float*)d_in[8];
    const float* gq  = (const float*)d_in[9];
    const float* bbq = (const float*)d_in[10];
    const float* gk  = (const float*)d_in[11];
    const float* bbk = (const float*)d_in[12];
    const float* qG1 = (const float*)d_in[13];
    const float* qG2 = (const float*)d_in[14];
    const float* kG1 = (const float*)d_in[15];
    const float* kG2 = (const float*)d_in[16];

    unsigned short* PHIQ  = (unsigned short*)d_ws;      // 32 MB [b,h,s,r]
    unsigned short* PHIKT = PHIQ + 16777216;            // 32 MB [b,h,r,s]
    unsigned short* VT    = PHIKT + 16777216;           // 32 MB [b,h*64+d,s]
    unsigned short* xb    = VT   + 16777216;            // 32 MB
    unsigned short* OAb   = xb   + 16777216;            // 32 MB
    unsigned short* WTf   = OAb  + 16777216;            // 2.5 MB
    unsigned short* WTp   = WTf  + 2560 * 512;          // 0.5 MB
    float* cvec = (float*)(WTp + 262144);               // 2,560 f
    float* KVP  = cvec + 2560;                          // 8 MB [bh,seg16][d][r]
    float* KSP  = KVP + 4194304;                        // 256 KB (16 segs used)
    float* KV   = KSP + 65536;                          // 512 KB [bh][d][r]
    float* KS   = KV + 131072;                          // 8 KB
    float* out  = (float*)d_out;

    hipLaunchKernelGGL(prep_all, dim3(9217), dim3(256), 0, stream,
                       x, xb, Wv, Wp, WTf, WTp,
                       Wq, bq, Wk, bk, bv, gq, bbq, gk, bbk,
                       qG1, qG2, kG1, kG2, cvec);
    hipLaunchKernelGGL(gemm_mfma_fused, dim3(5120), dim3(256), 0, stream,
                       xb, WTf, cvec, PHIQ, PHIKT, VT);
    hipLaunchKernelGGL(kv_mfma, dim3(32, 16), dim3(256), 0, stream,
                       PHIKT, VT, KVP, KSP);
    hipLaunchKernelGGL(kv_reduce, dim3(32, 8), dim3(256), 0, stream, KVP, KSP, KV, KS);
    hipLaunchKernelGGL(attn_mfma, dim3(32, 32), dim3(256), 0, stream,
                       PHIQ, KV, KS, OAb);
    hipLaunchKernelGGL(gemm_mfma_final, dim3(1024), dim3(256), 0, stream,
                       OAb, WTp, bp, out);
}